// Round 5
// baseline (718.280 us; speedup 1.0000x reference)
//
#include <hip/hip_runtime.h>
#include <hip/hip_bf16.h>

// FlashAttention fwd: B=4,H=12,S=4096,D=64 fp32. Reference semantics incl. the
// extra cur_scale factor, folded in log2-domain: p = exp2(s' + cm' - 2*mn'),
// s' = s*log2(e) (log2e folded into Q pre-scale; validated r3: absmax equal).
// Round-2 structure (422us) + log2 softmax + truncating P pack + hoisted LDS
// bases + QTILE=256/512-thread blocks (8 waves share K/V staging; staging VALU
// and barrier dead-time per unit compute halve).
// NO d_ws (harness re-poisons ws every iter -> cache-flush tax, r3 lesson).
// NO __any rescale branch, NO ones-row MFMA (r4 lesson: both regressed).

#define S_LEN 4096
#define HD    64
#define QTILE 256
#define KTILE 128
#define NKT   32

#define KSTR  72                    // u16 stride of K_lds rows (144 B)
#define VSTR  136                   // u16 stride of Vt rows (272 B)
#define VT_OFF (128 * KSTR)         // 9216 u16
#define SMEM_U16 (VT_OFF + HD * VSTR)  // 17920 u16 = 35840 B
#define OSTR  68                    // epilogue float stride

typedef __attribute__((ext_vector_type(8))) short bf16x8;
typedef __attribute__((ext_vector_type(4))) short bf16x4;
typedef __attribute__((ext_vector_type(4))) float f32x4;

// RNE f32->bf16 pair packed into u32 (staging/Q)
__device__ __forceinline__ unsigned int pk2(float f0, float f1) {
    unsigned int u0 = __builtin_bit_cast(unsigned int, f0);
    unsigned int u1 = __builtin_bit_cast(unsigned int, f1);
    u0 += 0x7FFFu + ((u0 >> 16) & 1u);
    u1 += 0x7FFFu + ((u1 >> 16) & 1u);
    return __builtin_amdgcn_perm(u1, u0, 0x07060302u);
}
// truncating pack (P only; P in [0,1], validated r3/r4): 1 instr per pair
__device__ __forceinline__ unsigned int pkt(float f0, float f1) {
    return __builtin_amdgcn_perm(__builtin_bit_cast(unsigned int, f1),
                                 __builtin_bit_cast(unsigned int, f0),
                                 0x07060302u);
}
__device__ __forceinline__ float e2(float x) {
#if __has_builtin(__builtin_amdgcn_exp2f)
    return __builtin_amdgcn_exp2f(x);
#else
    return __expf(x * 0.6931471805599453f);
#endif
}
__device__ __forceinline__ float rcp(float x) {
#if __has_builtin(__builtin_amdgcn_rcpf)
    return __builtin_amdgcn_rcpf(x);
#else
    return 1.0f / x;
#endif
}

__global__ __launch_bounds__(512, 4)
void fattn_kernel(const float* __restrict__ Q,
                  const float* __restrict__ K,
                  const float* __restrict__ V,
                  float* __restrict__ O) {
    __shared__ __align__(16) unsigned short smem[SMEM_U16];

    const int t    = threadIdx.x;
    const int wave = t >> 6;        // 0..7
    const int lane = t & 63;
    const int m    = lane & 15;
    const int quad = lane >> 4;

    const int qblk = blockIdx.x;    // 0..15
    const int head = blockIdx.y;    // 0..47
    const size_t hbase = (size_t)head * S_LEN * HD;

    unsigned short* const Kl = smem;
    unsigned short* const Vt = smem + VT_OFF;

    // ---- Q B-frags; scale = 0.125*log2(e) (log2-domain scores) ----
    bf16x8 qf[2][2];
    #pragma unroll
    for (int rt = 0; rt < 2; ++rt) {
        const float* qp = Q + hbase +
            (size_t)(qblk * QTILE + wave * 32 + rt * 16 + m) * HD + quad * 8;
        #pragma unroll
        for (int kd = 0; kd < 2; ++kd) {
            float4 a = *(const float4*)(qp + kd * 32);
            float4 b = *(const float4*)(qp + kd * 32 + 4);
            union { unsigned int u[4]; bf16x8 v; } cv;
            const float s = 0.18033688011112042f;   // 0.125 * log2(e)
            cv.u[0] = pk2(a.x * s, a.y * s);
            cv.u[1] = pk2(a.z * s, a.w * s);
            cv.u[2] = pk2(b.x * s, b.y * s);
            cv.u[3] = pk2(b.z * s, b.w * s);
            qf[rt][kd] = cv.v;
        }
    }

    f32x4 oacc[4][2];
    float mrow[2] = {-INFINITY, -INFINITY};
    float lrow[2] = {0.f, 0.f};
    #pragma unroll
    for (int dt = 0; dt < 4; ++dt)
        #pragma unroll
        for (int rt = 0; rt < 2; ++rt) oacc[dt][rt] = (f32x4){0.f,0.f,0.f,0.f};

    // ---- staging maps & hoisted LDS bases (all kt-invariant) ----
    const int r0k = t >> 3;                          // K: row 0..63 (+64i)
    const int c0k = (t & 7) * 8;                     // K: global col
    const int chk = ((t & 7) + ((t >> 3) & 7)) & 7;  // K: swizzled chunk
    const int vkey = t & 127;                        // V: key per thread
    const int vdb  = (t >> 7) * 16;                  // V: d-base 0/16/32/48
    unsigned short* const kwb = &Kl[r0k * KSTR + chk * 8];
    unsigned short* const vwp = &Vt[vdb * VSTR + vkey];
    const unsigned short* const kb0 = &Kl[m * KSTR + (((quad + m) & 7) << 3)];
    const unsigned short* const kb1 = &Kl[m * KSTR + (((4 + quad + m) & 7) << 3)];
    const unsigned short* const vrb = &Vt[m * VSTR + quad * 4];

    // ---- initial V prefetch (tile 0): 16 floats per thread ----
    float4 va[4];
    {
        const float* vp = V + hbase + (size_t)vkey * HD + vdb;
        #pragma unroll
        for (int j = 0; j < 4; ++j) va[j] = *(const float4*)(vp + j * 4);
    }

    for (int kt = 0; kt < NKT; ++kt) {
        __syncthreads();   // previous tile's LDS reads done

        // ---- V regs -> Vt (transposed b16 writes; 16 per thread) ----
        #pragma unroll
        for (int d = 0; d < 16; ++d) {
            float f = ((const float*)va)[d];
            unsigned int u = __builtin_bit_cast(unsigned int, f) + 0x8000u;
            vwp[d * VSTR] = (unsigned short)(u >> 16);
        }
        // ---- stage K tile kt (2 passes, b128 writes, swizzled chunks) ----
        {
            const float* kp = K + hbase + (size_t)(kt * KTILE + r0k) * HD + c0k;
            #pragma unroll
            for (int i = 0; i < 2; ++i) {
                float4 a = *(const float4*)(kp + i * 64 * HD);
                float4 b = *(const float4*)(kp + i * 64 * HD + 4);
                union { unsigned int u[4]; bf16x8 v; } cv;
                cv.u[0] = pk2(a.x, a.y); cv.u[1] = pk2(a.z, a.w);
                cv.u[2] = pk2(b.x, b.y); cv.u[3] = pk2(b.z, b.w);
                *(bf16x8*)(kwb + i * 64 * KSTR) = cv.v;
            }
        }
        __syncthreads();   // staging visible

        // ---- prefetch next tile's V (hidden behind compute) ----
        {
            int nk = (kt + 1 < NKT) ? kt + 1 : 0;
            const float* vp = V + hbase + (size_t)(nk * KTILE + vkey) * HD + vdb;
            #pragma unroll
            for (int j = 0; j < 4; ++j) va[j] = *(const float4*)(vp + j * 4);
        }

        // ---- S'^T = K.Q'^T (log2-domain scores) ----
        f32x4 sacc[8][2];
        #pragma unroll
        for (int k8 = 0; k8 < 8; ++k8)
            #pragma unroll
            for (int rt = 0; rt < 2; ++rt) sacc[k8][rt] = (f32x4){0.f,0.f,0.f,0.f};

        #pragma unroll
        for (int k8 = 0; k8 < 8; ++k8) {
            bf16x8 kf0 = *(const bf16x8*)(kb0 + k8 * 16 * KSTR);
            bf16x8 kf1 = *(const bf16x8*)(kb1 + k8 * 16 * KSTR);
            sacc[k8][0] = __builtin_amdgcn_mfma_f32_16x16x32_bf16(
                kf0, qf[0][0], sacc[k8][0], 0, 0, 0);
            sacc[k8][1] = __builtin_amdgcn_mfma_f32_16x16x32_bf16(
                kf0, qf[1][0], sacc[k8][1], 0, 0, 0);
            sacc[k8][0] = __builtin_amdgcn_mfma_f32_16x16x32_bf16(
                kf1, qf[0][1], sacc[k8][0], 0, 0, 0);
            sacc[k8][1] = __builtin_amdgcn_mfma_f32_16x16x32_bf16(
                kf1, qf[1][1], sacc[k8][1], 0, 0, 0);
        }

        // ---- online softmax (log2-domain, straight-line) ----
        unsigned int pkv[8][2][2];
        #pragma unroll
        for (int rt = 0; rt < 2; ++rt) {
            float cm = fmaxf(fmaxf(sacc[0][rt][0], sacc[0][rt][1]),
                             fmaxf(sacc[0][rt][2], sacc[0][rt][3]));
            #pragma unroll
            for (int k8 = 1; k8 < 8; ++k8) {
                float a = fmaxf(sacc[k8][rt][0], sacc[k8][rt][1]);
                float b = fmaxf(sacc[k8][rt][2], sacc[k8][rt][3]);
                cm = fmaxf(cm, fmaxf(a, b));
            }
            cm = fmaxf(cm, __shfl_xor(cm, 16, 64));
            cm = fmaxf(cm, __shfl_xor(cm, 32, 64));

            float mo = mrow[rt];
            float mn = fmaxf(mo, cm);
            float osc = e2(mo - mn);          // exp2(-inf)=0 on first tile
            float bias = cm - mn - mn;        // p = exp2(s' + cm' - 2mn')
            mrow[rt] = mn;

            #pragma unroll
            for (int dt = 0; dt < 4; ++dt) {
                oacc[dt][rt][0] *= osc; oacc[dt][rt][1] *= osc;
                oacc[dt][rt][2] *= osc; oacc[dt][rt][3] *= osc;
            }

            float rs = 0.f;
            #pragma unroll
            for (int k8 = 0; k8 < 8; ++k8) {
                float p0 = e2(sacc[k8][rt][0] + bias);
                float p1 = e2(sacc[k8][rt][1] + bias);
                float p2 = e2(sacc[k8][rt][2] + bias);
                float p3 = e2(sacc[k8][rt][3] + bias);
                rs += (p0 + p1) + (p2 + p3);
                pkv[k8][rt][0] = pkt(p0, p1);
                pkv[k8][rt][1] = pkt(p2, p3);
            }
            rs += __shfl_xor(rs, 16, 64);
            rs += __shfl_xor(rs, 32, 64);
            lrow[rt] = lrow[rt] * osc + rs;
        }

        // ---- O^T += V^T.P^T (P from registers; permuted key order) ----
        #pragma unroll
        for (int kc = 0; kc < 4; ++kc) {
            bf16x8 pf[2];
            #pragma unroll
            for (int rt = 0; rt < 2; ++rt) {
                union { unsigned int u[4]; bf16x8 v; } cv;
                cv.u[0] = pkv[2 * kc][rt][0];
                cv.u[1] = pkv[2 * kc][rt][1];
                cv.u[2] = pkv[2 * kc + 1][rt][0];
                cv.u[3] = pkv[2 * kc + 1][rt][1];
                pf[rt] = cv.v;
            }
            #pragma unroll
            for (int dt = 0; dt < 4; ++dt) {
                union { struct { bf16x4 lo, hi; } s; bf16x8 v; } uf;
                uf.s.lo = *(const bf16x4*)(vrb + dt * 16 * VSTR + kc * 32);
                uf.s.hi = *(const bf16x4*)(vrb + dt * 16 * VSTR + kc * 32 + 16);
                oacc[dt][0] = __builtin_amdgcn_mfma_f32_16x16x32_bf16(
                    uf.v, pf[0], oacc[dt][0], 0, 0, 0);
                oacc[dt][1] = __builtin_amdgcn_mfma_f32_16x16x32_bf16(
                    uf.v, pf[1], oacc[dt][1], 0, 0, 0);
            }
        }
    }

    // ---- epilogue: two 128-row phases through LDS (fits 35840 B) ----
    float* Ol = (float*)smem;
    const size_t obase = hbase + (size_t)(qblk * QTILE) * HD;
    #pragma unroll
    for (int ph = 0; ph < 2; ++ph) {
        __syncthreads();
        if ((wave >> 2) == ph) {
            #pragma unroll
            for (int rt = 0; rt < 2; ++rt) {
                float inv = rcp(lrow[rt]);
                #pragma unroll
                for (int dt = 0; dt < 4; ++dt)
                    #pragma unroll
                    for (int r = 0; r < 4; ++r)
                        Ol[((wave & 3) * 32 + rt * 16 + m) * OSTR +
                           dt * 16 + quad * 4 + r] = oacc[dt][rt][r] * inv;
            }
        }
        __syncthreads();
        #pragma unroll
        for (int s = 0; s < 4; ++s) {
            int lr  = s * 32 + (t >> 4);
            int col = (t & 15) * 4;
            *(float4*)&O[obase + (size_t)(ph * 128 + lr) * HD + col] =
                *(const float4*)&Ol[lr * OSTR + col];
        }
    }
}

extern "C" void kernel_launch(void* const* d_in, const int* in_sizes, int n_in,
                              void* d_out, int out_size, void* d_ws, size_t ws_size,
                              hipStream_t stream) {
    (void)in_sizes; (void)n_in; (void)d_ws; (void)ws_size; (void)out_size;
    const float* Q = (const float*)d_in[0];
    const float* K = (const float*)d_in[1];
    const float* V = (const float*)d_in[2];
    float* O = (float*)d_out;
    dim3 grid(S_LEN / QTILE, 4 * 12);   // 16 q-tiles x 48 heads = 768 blocks
    fattn_kernel<<<grid, 512, 0, stream>>>(Q, K, V, O);
}

// Round 6
// 484.212 us; speedup vs baseline: 1.4834x; 1.4834x over previous
//
#include <hip/hip_runtime.h>
#include <hip/hip_bf16.h>

// FlashAttention fwd: B=4,H=12,S=4096,D=64 fp32. Reference semantics incl. the
// extra cur_scale factor, folded in log2-domain: p = exp2(s' + cm' - 2*mn'),
// s' = s*log2(e) (log2e folded into Q pre-scale; validated r3-r5 absmax equal).
// Shell = round-2 (422us, 256 thr, QTILE=128, VGPR 84, no spills).
// Grafts: log2 softmax, truncating P pack, hoisted kt-invariant LDS bases.
// Lessons enforced: NO d_ws (harness poisons ws -> cache-flush tax, r3);
// NO __any branch / ones-row MFMA (r4); NO occupancy demand that caps VGPR<84
// (r5: launch_bounds(512,4) -> 64 VGPR -> scratch spills -> 1.2GB HBM traffic).

#define S_LEN 4096
#define HD    64
#define QTILE 128
#define KTILE 128
#define NKT   32

#define KSTR  72                    // u16 stride of K_lds rows (144 B)
#define VSTR  136                   // u16 stride of Vt rows (272 B)
#define VT_OFF (128 * KSTR)         // 9216 u16
#define SMEM_U16 (VT_OFF + HD * VSTR)  // 17920 u16 = 35840 B
#define OSTR  68                    // epilogue float stride

typedef __attribute__((ext_vector_type(8))) short bf16x8;
typedef __attribute__((ext_vector_type(4))) short bf16x4;
typedef __attribute__((ext_vector_type(4))) float f32x4;

// RNE f32->bf16 pair packed into u32 (staging/Q)
__device__ __forceinline__ unsigned int pk2(float f0, float f1) {
    unsigned int u0 = __builtin_bit_cast(unsigned int, f0);
    unsigned int u1 = __builtin_bit_cast(unsigned int, f1);
    u0 += 0x7FFFu + ((u0 >> 16) & 1u);
    u1 += 0x7FFFu + ((u1 >> 16) & 1u);
    return __builtin_amdgcn_perm(u1, u0, 0x07060302u);
}
// truncating pack (P only; P in [0,1]): 1 instr per pair
__device__ __forceinline__ unsigned int pkt(float f0, float f1) {
    return __builtin_amdgcn_perm(__builtin_bit_cast(unsigned int, f1),
                                 __builtin_bit_cast(unsigned int, f0),
                                 0x07060302u);
}
__device__ __forceinline__ float e2(float x) {
#if __has_builtin(__builtin_amdgcn_exp2f)
    return __builtin_amdgcn_exp2f(x);
#else
    return __expf(x * 0.6931471805599453f);
#endif
}
__device__ __forceinline__ float rcp(float x) {
#if __has_builtin(__builtin_amdgcn_rcpf)
    return __builtin_amdgcn_rcpf(x);
#else
    return 1.0f / x;
#endif
}

__global__ __launch_bounds__(256, 3)
void fattn_kernel(const float* __restrict__ Q,
                  const float* __restrict__ K,
                  const float* __restrict__ V,
                  float* __restrict__ O) {
    __shared__ __align__(16) unsigned short smem[SMEM_U16];

    const int t    = threadIdx.x;
    const int wave = t >> 6;
    const int lane = t & 63;
    const int m    = lane & 15;
    const int quad = lane >> 4;

    const int qblk = blockIdx.x;
    const int head = blockIdx.y;
    const size_t hbase = (size_t)head * S_LEN * HD;

    unsigned short* const Kl = smem;
    unsigned short* const Vt = smem + VT_OFF;

    // ---- Q B-frags; scale = 0.125*log2(e) (log2-domain scores) ----
    bf16x8 qf[2][2];
    #pragma unroll
    for (int rt = 0; rt < 2; ++rt) {
        const float* qp = Q + hbase +
            (size_t)(qblk * QTILE + wave * 32 + rt * 16 + m) * HD + quad * 8;
        #pragma unroll
        for (int kd = 0; kd < 2; ++kd) {
            float4 a = *(const float4*)(qp + kd * 32);
            float4 b = *(const float4*)(qp + kd * 32 + 4);
            union { unsigned int u[4]; bf16x8 v; } cv;
            const float s = 0.18033688011112042f;   // 0.125 * log2(e)
            cv.u[0] = pk2(a.x * s, a.y * s);
            cv.u[1] = pk2(a.z * s, a.w * s);
            cv.u[2] = pk2(b.x * s, b.y * s);
            cv.u[3] = pk2(b.z * s, b.w * s);
            qf[rt][kd] = cv.v;
        }
    }

    f32x4 oacc[4][2];
    float mrow[2] = {-INFINITY, -INFINITY};
    float lrow[2] = {0.f, 0.f};
    #pragma unroll
    for (int dt = 0; dt < 4; ++dt)
        #pragma unroll
        for (int rt = 0; rt < 2; ++rt) oacc[dt][rt] = (f32x4){0.f,0.f,0.f,0.f};

    // ---- staging maps & hoisted LDS bases (all kt-invariant) ----
    const int r0k = t >> 3;                          // K: row 0..31 (+32i)
    const int c0k = (t & 7) * 8;                     // K: global col
    const int chk = ((t & 7) + ((t >> 3) & 7)) & 7;  // K: swizzled chunk
    const int vkey = t & 127;                        // V: key per thread
    const int vdb  = (t >> 7) * 32;                  // V: d-base 0/32
    unsigned short* const kwb = &Kl[r0k * KSTR + chk * 8];
    unsigned short* const vwp = &Vt[vdb * VSTR + vkey];
    const unsigned short* const kb0 = &Kl[m * KSTR + (((quad + m) & 7) << 3)];
    const unsigned short* const kb1 = &Kl[m * KSTR + (((4 + quad + m) & 7) << 3)];
    const unsigned short* const vrb = &Vt[m * VSTR + quad * 4];

    // ---- initial V prefetch (tile 0): 32 floats per thread ----
    float4 va[4][2];
    {
        const float* vp = V + hbase + (size_t)vkey * HD + vdb;
        #pragma unroll
        for (int i = 0; i < 4; ++i) {
            va[i][0] = *(const float4*)(vp + i * 8);
            va[i][1] = *(const float4*)(vp + i * 8 + 4);
        }
    }

    for (int kt = 0; kt < NKT; ++kt) {
        __syncthreads();   // previous tile's LDS reads done

        // ---- V regs -> Vt (transposed b16 writes) ----
        #pragma unroll
        for (int i = 0; i < 4; ++i) {
            #pragma unroll
            for (int j = 0; j < 8; ++j) {
                float f = ((const float*)&va[i][j >> 2])[j & 3];
                unsigned int u = __builtin_bit_cast(unsigned int, f) + 0x8000u;
                vwp[(i * 8 + j) * VSTR] = (unsigned short)(u >> 16);
            }
        }
        // ---- stage K tile kt (b128 writes, swizzled chunks) ----
        {
            const float* kp = K + hbase + (size_t)(kt * KTILE + r0k) * HD + c0k;
            #pragma unroll
            for (int i = 0; i < 4; ++i) {
                float4 a = *(const float4*)(kp + i * 32 * HD);
                float4 b = *(const float4*)(kp + i * 32 * HD + 4);
                union { unsigned int u[4]; bf16x8 v; } cv;
                cv.u[0] = pk2(a.x, a.y); cv.u[1] = pk2(a.z, a.w);
                cv.u[2] = pk2(b.x, b.y); cv.u[3] = pk2(b.z, b.w);
                *(bf16x8*)(kwb + i * 32 * KSTR) = cv.v;
            }
        }
        __syncthreads();   // staging visible

        // ---- prefetch next tile's V (hidden behind compute) ----
        {
            int nk = (kt + 1 < NKT) ? kt + 1 : 0;
            const float* vp = V + hbase + (size_t)(nk * KTILE + vkey) * HD + vdb;
            #pragma unroll
            for (int i = 0; i < 4; ++i) {
                va[i][0] = *(const float4*)(vp + i * 8);
                va[i][1] = *(const float4*)(vp + i * 8 + 4);
            }
        }

        // ---- S'^T = K.Q'^T (log2-domain scores) ----
        f32x4 sacc[8][2];
        #pragma unroll
        for (int k8 = 0; k8 < 8; ++k8)
            #pragma unroll
            for (int rt = 0; rt < 2; ++rt) sacc[k8][rt] = (f32x4){0.f,0.f,0.f,0.f};

        #pragma unroll
        for (int k8 = 0; k8 < 8; ++k8) {
            bf16x8 kf0 = *(const bf16x8*)(kb0 + k8 * 16 * KSTR);
            bf16x8 kf1 = *(const bf16x8*)(kb1 + k8 * 16 * KSTR);
            sacc[k8][0] = __builtin_amdgcn_mfma_f32_16x16x32_bf16(
                kf0, qf[0][0], sacc[k8][0], 0, 0, 0);
            sacc[k8][1] = __builtin_amdgcn_mfma_f32_16x16x32_bf16(
                kf0, qf[1][0], sacc[k8][1], 0, 0, 0);
            sacc[k8][0] = __builtin_amdgcn_mfma_f32_16x16x32_bf16(
                kf1, qf[0][1], sacc[k8][0], 0, 0, 0);
            sacc[k8][1] = __builtin_amdgcn_mfma_f32_16x16x32_bf16(
                kf1, qf[1][1], sacc[k8][1], 0, 0, 0);
        }

        // ---- online softmax (log2-domain, straight-line) ----
        unsigned int pkv[8][2][2];
        #pragma unroll
        for (int rt = 0; rt < 2; ++rt) {
            float cm = fmaxf(fmaxf(sacc[0][rt][0], sacc[0][rt][1]),
                             fmaxf(sacc[0][rt][2], sacc[0][rt][3]));
            #pragma unroll
            for (int k8 = 1; k8 < 8; ++k8) {
                float a = fmaxf(sacc[k8][rt][0], sacc[k8][rt][1]);
                float b = fmaxf(sacc[k8][rt][2], sacc[k8][rt][3]);
                cm = fmaxf(cm, fmaxf(a, b));
            }
            cm = fmaxf(cm, __shfl_xor(cm, 16, 64));
            cm = fmaxf(cm, __shfl_xor(cm, 32, 64));

            float mo = mrow[rt];
            float mn = fmaxf(mo, cm);
            float osc = e2(mo - mn);          // exp2(-inf)=0 on first tile
            float bias = cm - mn - mn;        // p = exp2(s' + cm' - 2mn')
            mrow[rt] = mn;

            #pragma unroll
            for (int dt = 0; dt < 4; ++dt) {
                oacc[dt][rt][0] *= osc; oacc[dt][rt][1] *= osc;
                oacc[dt][rt][2] *= osc; oacc[dt][rt][3] *= osc;
            }

            float rs = 0.f;
            #pragma unroll
            for (int k8 = 0; k8 < 8; ++k8) {
                float p0 = e2(sacc[k8][rt][0] + bias);
                float p1 = e2(sacc[k8][rt][1] + bias);
                float p2 = e2(sacc[k8][rt][2] + bias);
                float p3 = e2(sacc[k8][rt][3] + bias);
                rs += (p0 + p1) + (p2 + p3);
                pkv[k8][rt][0] = pkt(p0, p1);
                pkv[k8][rt][1] = pkt(p2, p3);
            }
            rs += __shfl_xor(rs, 16, 64);
            rs += __shfl_xor(rs, 32, 64);
            lrow[rt] = lrow[rt] * osc + rs;
        }

        // ---- O^T += V^T.P^T (P from registers; permuted key order) ----
        #pragma unroll
        for (int kc = 0; kc < 4; ++kc) {
            bf16x8 pf[2];
            #pragma unroll
            for (int rt = 0; rt < 2; ++rt) {
                union { unsigned int u[4]; bf16x8 v; } cv;
                cv.u[0] = pkv[2 * kc][rt][0];
                cv.u[1] = pkv[2 * kc][rt][1];
                cv.u[2] = pkv[2 * kc + 1][rt][0];
                cv.u[3] = pkv[2 * kc + 1][rt][1];
                pf[rt] = cv.v;
            }
            #pragma unroll
            for (int dt = 0; dt < 4; ++dt) {
                union { struct { bf16x4 lo, hi; } s; bf16x8 v; } uf;
                uf.s.lo = *(const bf16x4*)(vrb + dt * 16 * VSTR + kc * 32);
                uf.s.hi = *(const bf16x4*)(vrb + dt * 16 * VSTR + kc * 32 + 16);
                oacc[dt][0] = __builtin_amdgcn_mfma_f32_16x16x32_bf16(
                    uf.v, pf[0], oacc[dt][0], 0, 0, 0);
                oacc[dt][1] = __builtin_amdgcn_mfma_f32_16x16x32_bf16(
                    uf.v, pf[1], oacc[dt][1], 0, 0, 0);
            }
        }
    }

    // ---- epilogue: O^T/l -> LDS transpose -> coalesced float4 stores ----
    __syncthreads();
    float* Ol = (float*)smem;
    #pragma unroll
    for (int rt = 0; rt < 2; ++rt) {
        float inv = rcp(lrow[rt]);
        #pragma unroll
        for (int dt = 0; dt < 4; ++dt)
            #pragma unroll
            for (int r = 0; r < 4; ++r)
                Ol[(wave * 32 + rt * 16 + m) * OSTR + dt * 16 + quad * 4 + r] =
                    oacc[dt][rt][r] * inv;
    }
    __syncthreads();
    const size_t obase = hbase + (size_t)(qblk * QTILE) * HD;
    #pragma unroll
    for (int s = 0; s < 8; ++s) {
        int row = s * 16 + (t >> 4);
        int col = (t & 15) * 4;
        *(float4*)&O[obase + (size_t)row * HD + col] =
            *(const float4*)&Ol[row * OSTR + col];
    }
}

extern "C" void kernel_launch(void* const* d_in, const int* in_sizes, int n_in,
                              void* d_out, int out_size, void* d_ws, size_t ws_size,
                              hipStream_t stream) {
    (void)in_sizes; (void)n_in; (void)d_ws; (void)ws_size; (void)out_size;
    const float* Q = (const float*)d_in[0];
    const float* K = (const float*)d_in[1];
    const float* V = (const float*)d_in[2];
    float* O = (float*)d_out;
    dim3 grid(S_LEN / QTILE, 4 * 12);   // 32 q-tiles x 48 heads
    fattn_kernel<<<grid, 256, 0, stream>>>(Q, K, V, O);
}